// Round 1
// baseline (233.682 us; speedup 1.0000x reference)
//
#include <hip/hip_runtime.h>

#define NC 1024
#define DY 16
#define NG 65536  // 256*256 grid points

// One thread per grid point. mi = blockIdx.y so all xc/yc addresses are
// wave-uniform -> scalar loads (s_load_dwordx4) through the constant cache.
__global__ __launch_bounds__(256) void setconv_kernel(
    const float* __restrict__ xc,   // [m, NC, 2]
    const float* __restrict__ yc,   // [m, NC, DY]
    const float* __restrict__ lsp,  // [2] lengthscale_param
    float* __restrict__ out_grid,   // [m, 256, 256, 2]
    float* __restrict__ out_z)      // [m, 256, 256, 17]
{
    const int mi = blockIdx.y;
    const int g  = blockIdx.x * blockDim.x + threadIdx.x;  // 0..65535
    const int i  = g >> 8;
    const int j  = g & 255;

    // lengthscale = 1e-5 + softplus(param), per dim (computed per thread; amortized)
    const float l0 = 1e-5f + log1pf(__expf(lsp[0]));
    const float l1 = 1e-5f + log1pf(__expf(lsp[1]));
    const float inv0 = 1.0f / l0;
    const float inv1 = 1.0f / l1;

    // grid coords: x_mid + (idx - 128)/64, exact in fp32
    const float gx = 1.0f + (float)(i - 128) * 0.015625f;
    const float gy = 1.0f + (float)(j - 128) * 0.015625f;

    // output 0: broadcast grid
    {
        float2* og = (float2*)out_grid + (mi * NG + g);
        *og = make_float2(gx, gy);
    }

    const float ax = gx * inv0;
    const float ay = gy * inv1;

    const float2* __restrict__ xcm = (const float2*)(xc + mi * NC * 2);
    const float*  __restrict__ ycm = yc + mi * NC * DY;

    float acc[17];
#pragma unroll
    for (int k = 0; k < 17; ++k) acc[k] = 0.0f;

    // exp(-0.5*s) = exp2(-0.72134752*s)
    const float K2 = -0.72134752f;

#pragma unroll 2
    for (int c = 0; c < NC; ++c) {
        const float2 cxy = xcm[c];                // uniform -> s_load
        const float t0 = ax - cxy.x * inv0;
        const float t1 = ay - cxy.y * inv1;
        const float s  = fmaf(t0, t0, t1 * t1);
        const float w  = __builtin_amdgcn_exp2f(K2 * s);

        const float4* __restrict__ y4 = (const float4*)(ycm + c * DY);  // 64B aligned, uniform
        const float4 y0 = y4[0];
        const float4 y1 = y4[1];
        const float4 y2 = y4[2];
        const float4 y3 = y4[3];

        acc[0]  = fmaf(w, y0.x, acc[0]);
        acc[1]  = fmaf(w, y0.y, acc[1]);
        acc[2]  = fmaf(w, y0.z, acc[2]);
        acc[3]  = fmaf(w, y0.w, acc[3]);
        acc[4]  = fmaf(w, y1.x, acc[4]);
        acc[5]  = fmaf(w, y1.y, acc[5]);
        acc[6]  = fmaf(w, y1.z, acc[6]);
        acc[7]  = fmaf(w, y1.w, acc[7]);
        acc[8]  = fmaf(w, y2.x, acc[8]);
        acc[9]  = fmaf(w, y2.y, acc[9]);
        acc[10] = fmaf(w, y2.z, acc[10]);
        acc[11] = fmaf(w, y2.w, acc[11]);
        acc[12] = fmaf(w, y3.x, acc[12]);
        acc[13] = fmaf(w, y3.y, acc[13]);
        acc[14] = fmaf(w, y3.z, acc[14]);
        acc[15] = fmaf(w, y3.w, acc[15]);
        acc[16] += w;  // density channel (ones)
    }

    float* __restrict__ oz = out_z + (size_t)(mi * NG + g) * 17;
#pragma unroll
    for (int k = 0; k < 17; ++k) oz[k] = acc[k];
}

extern "C" void kernel_launch(void* const* d_in, const int* in_sizes, int n_in,
                              void* d_out, int out_size, void* d_ws, size_t ws_size,
                              hipStream_t stream) {
    const float* xc  = (const float*)d_in[0];   // [m, 1024, 2]
    const float* yc  = (const float*)d_in[1];   // [m, 1024, 16]
    // d_in[2] = xt — unused by the reference output
    const float* lsp = (const float*)d_in[3];   // [2]

    const int m = in_sizes[0] / (NC * 2);       // = 2

    float* out_grid = (float*)d_out;                    // m*65536*2 floats
    float* out_z    = (float*)d_out + (size_t)m * NG * 2;

    dim3 grid(NG / 256, m);
    dim3 block(256);
    hipLaunchKernelGGL(setconv_kernel, grid, block, 0, stream,
                       xc, yc, lsp, out_grid, out_z);
}

// Round 2
// 147.983 us; speedup vs baseline: 1.5791x; 1.5791x over previous
//
#include <hip/hip_runtime.h>

#define NC 1024
#define DY 16
#define NG 65536      // 256*256 grid points
#define CTILE 512     // contexts staged in LDS per tile
#define CSTRIDE 20    // floats per context in LDS (16 y + sx + sy + 2 pad) = 80B

typedef float v2f __attribute__((ext_vector_type(2)));

// One thread per grid point; contexts staged in LDS (broadcast reads pipeline
// via in-order DS + partial lgkmcnt waits, unlike SMEM which drains lgkmcnt(0)).
__global__ __launch_bounds__(256) void setconv_kernel(
    const float* __restrict__ xc,   // [m, NC, 2]
    const float* __restrict__ yc,   // [m, NC, DY]
    const float* __restrict__ lsp,  // [2] lengthscale_param
    float* __restrict__ out_grid,   // [m, 256, 256, 2]
    float* __restrict__ out_z)      // [m, 256, 256, 17]
{
    __shared__ __align__(16) float sm[CTILE * CSTRIDE];  // 40 KB

    const int mi = blockIdx.y;
    const int g  = blockIdx.x * blockDim.x + threadIdx.x;  // 0..65535
    const int i  = g >> 8;
    const int j  = g & 255;

    // lengthscale = 1e-5 + softplus(param)
    const float l0 = 1e-5f + log1pf(__expf(lsp[0]));
    const float l1 = 1e-5f + log1pf(__expf(lsp[1]));
    // fold exp(-0.5*s) = exp2(-0.72134752*s) into coordinate pre-scaling:
    const float R  = 0.84932184f;          // sqrt(log2(e)/2)
    const float s0 = R / l0;
    const float s1 = R / l1;

    // grid coords: x_mid + (idx - 128)/64, exact in fp32
    const float gx = 1.0f + (float)(i - 128) * 0.015625f;
    const float gy = 1.0f + (float)(j - 128) * 0.015625f;

    // output 0: broadcast grid
    {
        float2* og = (float2*)out_grid + (mi * NG + g);
        *og = make_float2(gx, gy);
    }

    const float gxp = gx * s0;
    const float gyp = gy * s1;

    const float2* __restrict__ xcm = (const float2*)(xc + mi * NC * 2);
    const float*  __restrict__ ycm = yc + mi * NC * DY;

    v2f acc2[8];
#pragma unroll
    for (int k = 0; k < 8; ++k) acc2[k] = (v2f){0.0f, 0.0f};
    float accd = 0.0f;

    for (int cbase = 0; cbase < NC; cbase += CTILE) {
        // ---- stage tile into LDS (coalesced float4 for y, float2 for coords) ----
        for (int t = threadIdx.x; t < CTILE * 4; t += 256) {
            const int c = t >> 2, q = t & 3;
            const float4 v = ((const float4*)(ycm + (size_t)(cbase + c) * DY))[q];
            *(float4*)&sm[c * CSTRIDE + q * 4] = v;
        }
        for (int t = threadIdx.x; t < CTILE; t += 256) {
            const float2 cxy = xcm[cbase + t];
            sm[t * CSTRIDE + 16] = cxy.x * s0;
            sm[t * CSTRIDE + 17] = cxy.y * s1;
        }
        __syncthreads();

        // ---- inner loop over staged contexts ----
#pragma unroll 4
        for (int c = 0; c < CTILE; ++c) {
            const float* __restrict__ p = &sm[c * CSTRIDE];
            const float sx = p[16];
            const float sy = p[17];
            const float u0 = gxp - sx;
            const float u1 = gyp - sy;
            const float s  = fmaf(u1, u1, u0 * u0);
            const float w  = __builtin_amdgcn_exp2f(-s);
            const v2f  w2  = (v2f){w, w};
#pragma unroll
            for (int k = 0; k < 8; ++k) {
                const v2f y2 = *(const v2f*)&p[k * 2];
                acc2[k] = __builtin_elementwise_fma(w2, y2, acc2[k]);
            }
            accd += w;
        }
        __syncthreads();
    }

    float* __restrict__ oz = out_z + (size_t)(mi * NG + g) * 17;
#pragma unroll
    for (int k = 0; k < 8; ++k) {
        oz[2 * k]     = acc2[k].x;
        oz[2 * k + 1] = acc2[k].y;
    }
    oz[16] = accd;
}

extern "C" void kernel_launch(void* const* d_in, const int* in_sizes, int n_in,
                              void* d_out, int out_size, void* d_ws, size_t ws_size,
                              hipStream_t stream) {
    const float* xc  = (const float*)d_in[0];   // [m, 1024, 2]
    const float* yc  = (const float*)d_in[1];   // [m, 1024, 16]
    // d_in[2] = xt — unused by the reference output
    const float* lsp = (const float*)d_in[3];   // [2]

    const int m = in_sizes[0] / (NC * 2);       // = 2

    float* out_grid = (float*)d_out;                    // m*65536*2 floats
    float* out_z    = (float*)d_out + (size_t)m * NG * 2;

    dim3 grid(NG / 256, m);
    dim3 block(256);
    hipLaunchKernelGGL(setconv_kernel, grid, block, 0, stream,
                       xc, yc, lsp, out_grid, out_z);
}

// Round 3
// 91.666 us; speedup vs baseline: 2.5493x; 1.6144x over previous
//
#include <hip/hip_runtime.h>

#define NC 1024
#define DY 16
#define NG 65536       // 256*256 grid points
#define KTILE 256      // contexts staged in LDS per tile
#define YSTRIDE 264    // padded bf16 row stride (breaks 512B power-of-2 stride)

typedef float v2f __attribute__((ext_vector_type(2)));
typedef float v4f __attribute__((ext_vector_type(4)));
typedef short s8v __attribute__((ext_vector_type(8)));

static __device__ __forceinline__ short f2bf_rne(float f) {
    unsigned u = __builtin_bit_cast(unsigned, f);
    u += 0x7FFF + ((u >> 16) & 1);
    return (short)(u >> 16);
}
static __device__ __forceinline__ unsigned pack_bf2(float lo, float hi) {
    // truncating f32->bf16 pack: D = (bf16(hi)<<16) | bf16(lo), one v_perm_b32
    return __builtin_amdgcn_perm(__builtin_bit_cast(unsigned, hi),
                                 __builtin_bit_cast(unsigned, lo), 0x07060302u);
}

// One wave per 16-grid-point M-tile. Weights computed in-register directly in
// MFMA A-fragment layout (A[m=lane&15][k=quad*8+j]); Y^T staged bf16 in LDS so
// the B-fragment (B[k=quad*8+j][n=lane&15]) is one ds_read_b128. Density
// channel = weight-sum via shfl quad-reduce (no second MFMA).
__global__ __launch_bounds__(256) void setconv_mfma(
    const float* __restrict__ xc,   // [m, NC, 2]
    const float* __restrict__ yc,   // [m, NC, DY]
    const float* __restrict__ lsp,  // [2]
    float* __restrict__ out_grid,   // [m, 256, 256, 2]
    float* __restrict__ out_z)      // [m, 256, 256, 17]
{
    __shared__ __align__(16) short Yt[DY * YSTRIDE];   // 8448 B
    __shared__ __align__(16) float sxs[KTILE];         // 1 KB
    __shared__ __align__(16) float sys[KTILE];         // 1 KB

    const int mi   = blockIdx.y;
    const int tid  = threadIdx.x;
    const int wave = tid >> 6;
    const int lane = tid & 63;
    const int q    = lane >> 4;     // quad 0..3
    const int r    = lane & 15;

    const int g0b = blockIdx.x * 64;       // block's first grid point
    const int g0w = g0b + wave * 16;       // this wave's M-tile base

    const float l0 = 1e-5f + log1pf(__expf(lsp[0]));
    const float l1 = 1e-5f + log1pf(__expf(lsp[1]));
    const float R  = 0.84932184f;          // sqrt(log2(e)/2)
    const float s0 = R / l0;
    const float s1 = R / l1;

    // output 0: grid coords (threads 0..63 cover the block's 64 grid points)
    if (tid < 64) {
        const int g = g0b + tid;
        const float gx = 1.0f + (float)((g >> 8) - 128) * 0.015625f;
        const float gy = 1.0f + (float)((g & 255) - 128) * 0.015625f;
        ((float2*)out_grid)[(size_t)mi * NG + g] = make_float2(gx, gy);
    }

    // this lane's grid row (row r of the M-tile), pre-scaled
    const int   gme = g0w + r;
    const float gxp = (1.0f + (float)((gme >> 8) - 128) * 0.015625f) * s0;
    const float gyp = (1.0f + (float)((gme & 255) - 128) * 0.015625f) * s1;
    const v2f gx2 = {gxp, gxp};
    const v2f gy2 = {gyp, gyp};

    v4f acc = {0.f, 0.f, 0.f, 0.f};
    float wsA = 0.f, wsB = 0.f;

    for (int cbase = 0; cbase < NC; cbase += KTILE) {
        // ---- stage tile: Y^T (bf16) + pre-scaled coords ----
        {
            const float4* yrow = (const float4*)(yc + ((size_t)mi * NC + cbase + tid) * DY);
            const float4 y0 = yrow[0], y1 = yrow[1], y2 = yrow[2], y3 = yrow[3];
            const short b[16] = {
                f2bf_rne(y0.x), f2bf_rne(y0.y), f2bf_rne(y0.z), f2bf_rne(y0.w),
                f2bf_rne(y1.x), f2bf_rne(y1.y), f2bf_rne(y1.z), f2bf_rne(y1.w),
                f2bf_rne(y2.x), f2bf_rne(y2.y), f2bf_rne(y2.z), f2bf_rne(y2.w),
                f2bf_rne(y3.x), f2bf_rne(y3.y), f2bf_rne(y3.z), f2bf_rne(y3.w)};
#pragma unroll
            for (int ch = 0; ch < 16; ++ch) Yt[ch * YSTRIDE + tid] = b[ch];

            const float2 cxy = ((const float2*)xc)[(size_t)mi * NC + cbase + tid];
            sxs[tid] = cxy.x * s0;
            sys[tid] = cxy.y * s1;
        }
        __syncthreads();

        // ---- 8 K-steps of 32 contexts ----
#pragma unroll
        for (int ks = 0; ks < 8; ++ks) {
            const int kb = ks * 32 + q * 8;   // this quad's k-slice base
            const float4 sxa = *(const float4*)&sxs[kb];
            const float4 sxb = *(const float4*)&sxs[kb + 4];
            const float4 sya = *(const float4*)&sys[kb];
            const float4 syb = *(const float4*)&sys[kb + 4];
            const s8v bfrag = *(const s8v*)&Yt[r * YSTRIDE + kb];

            const v2f sxp[4] = {{sxa.x, sxa.y}, {sxa.z, sxa.w}, {sxb.x, sxb.y}, {sxb.z, sxb.w}};
            const v2f syp[4] = {{sya.x, sya.y}, {sya.z, sya.w}, {syb.x, syb.y}, {syb.z, syb.w}};

            unsigned pk[4];
#pragma unroll
            for (int jj = 0; jj < 4; ++jj) {
                const v2f ux = gx2 - sxp[jj];
                const v2f uy = gy2 - syp[jj];
                v2f sq = ux * ux;
                sq = __builtin_elementwise_fma(uy, uy, sq);
                const float e0 = __builtin_amdgcn_exp2f(-sq.x);
                const float e1 = __builtin_amdgcn_exp2f(-sq.y);
                wsA += e0;
                wsB += e1;
                pk[jj] = pack_bf2(e0, e1);
            }
            union { unsigned u[4]; s8v s; } af;
            af.u[0] = pk[0]; af.u[1] = pk[1]; af.u[2] = pk[2]; af.u[3] = pk[3];

            acc = __builtin_amdgcn_mfma_f32_16x16x32_bf16(af.s, bfrag, acc, 0, 0, 0);
        }
        __syncthreads();
    }

    // ---- epilogue ----
    float wsum = wsA + wsB;
    wsum += __shfl_xor(wsum, 16, 64);   // reduce across quads (lanes r,r+16,r+32,r+48)
    wsum += __shfl_xor(wsum, 32, 64);

    float* __restrict__ ozb = out_z + ((size_t)mi * NG + g0w) * 17;
#pragma unroll
    for (int reg = 0; reg < 4; ++reg) {
        const int row = q * 4 + reg;    // C/D: col=lane&15, row=quad*4+reg (m89-verified)
        ozb[row * 17 + r] = acc[reg];
    }
    if (lane < 16) ozb[lane * 17 + 16] = wsum;
}

extern "C" void kernel_launch(void* const* d_in, const int* in_sizes, int n_in,
                              void* d_out, int out_size, void* d_ws, size_t ws_size,
                              hipStream_t stream) {
    const float* xc  = (const float*)d_in[0];   // [m, 1024, 2]
    const float* yc  = (const float*)d_in[1];   // [m, 1024, 16]
    // d_in[2] = xt — unused by the reference output
    const float* lsp = (const float*)d_in[3];   // [2]

    const int m = in_sizes[0] / (NC * 2);       // = 2

    float* out_grid = (float*)d_out;                        // m*NG*2 floats
    float* out_z    = (float*)d_out + (size_t)m * NG * 2;   // m*NG*17 floats

    dim3 grid(NG / 64, m);   // one wave per 16 grid points, 4 waves/block
    dim3 block(256);
    hipLaunchKernelGGL(setconv_mfma, grid, block, 0, stream,
                       xc, yc, lsp, out_grid, out_z);
}